// Round 8
// baseline (670.320 us; speedup 1.0000x reference)
//
#include <hip/hip_runtime.h>
#include <hip/hip_bf16.h>

#define B_   2
#define S_   2048
#define D_   2048
#define H_   16
#define KV_  4
#define KQD_ 96
#define VD_  128
#define NQK_ 1920            // H*KQD + KV*KQD = 1536 + 384
#define M_   4096            // B*S

typedef __attribute__((ext_vector_type(8))) short bf16x8;
typedef __attribute__((ext_vector_type(4))) short bf16x4;
typedef __attribute__((ext_vector_type(4))) float f32x4;

__device__ __forceinline__ short f2bf(float f) {
    union { float f; unsigned u; } v; v.f = f;
    unsigned r = (v.u + 0x7fffu + ((v.u >> 16) & 1u)) >> 16;
    return (short)r;
}
__device__ __forceinline__ float bf2f(short s) {
    union { unsigned u; float f; } v; v.u = ((unsigned)(unsigned short)s) << 16;
    return v.f;
}

__device__ __forceinline__ void glds16(const void* g, void* l) {
    __builtin_amdgcn_global_load_lds(
        (__attribute__((address_space(1))) void*)(g),
        (__attribute__((address_space(3))) void*)(l), 16, 0, 0);
}

// DPP-based 16-lane sum (attn epilogue)
template <int CTRL>
__device__ __forceinline__ float dppf(float x) {
    return __int_as_float(__builtin_amdgcn_update_dpp(
        0, __float_as_int(x), CTRL, 0xF, 0xF, true));
}
__device__ __forceinline__ float rsum16(float x) {
    x += dppf<0xB1>(x);     // quad_perm xor1
    x += dppf<0x4E>(x);     // quad_perm xor2
    x += dppf<0x124>(x);    // row_ror:4
    x += dppf<0x128>(x);    // row_ror:8
    return x;
}

// ---------------------------------------------------------------------------
// fp32 -> bf16 for all five inputs in one launch; dests contiguous in ws.
// ---------------------------------------------------------------------------
__global__ __launch_bounds__(256) void cvt_all(
    const float* __restrict__ hs, const float* __restrict__ wq,
    const float* __restrict__ wk, const float* __restrict__ wv,
    const float* __restrict__ wo, short* __restrict__ dst)
{
    int i = blockIdx.x * 256 + threadIdx.x;
    if (i >= 4390912) return;
    const float* s; int off;
    if      (i < 2097152) { s = hs; off = i; }
    else if (i < 2883584) { s = wq; off = i - 2097152; }
    else if (i < 3080192) { s = wk; off = i - 2883584; }
    else if (i < 3342336) { s = wv; off = i - 3080192; }
    else                  { s = wo; off = i - 3342336; }
    float4 v = ((const float4*)s)[off];
    bf16x4 o;
    o.x = f2bf(v.x); o.y = f2bf(v.y); o.z = f2bf(v.z); o.w = f2bf(v.w);
    ((bf16x4*)dst)[i] = o;
}

// ---------------------------------------------------------------------------
// GEMM: C[M x N] = A[M x K] * W[N x K]^T  (bf16 in, fp32 acc)
// 128x64 tile, 256 thr (4 waves = 2M x 2N, wave-tile 64x32, acc[4][2]).
// Granularity proven R5: gemm3 32x38=1216 blocks (95% balance),
// gemm2 32x32=1024 (100%). LDS 48 KB -> 3 blocks/CU.
// T3+T4 pipeline (counted vmcnt, never 0 in main loop), T2 source-side
// XOR swizzle (conflicts == 0 measured), T1 bijective XCD swizzle.
// OUT==2: fp32 row-major.  OUT==3: fused QKV (n0<NQK_ row-major bf16;
// n0>=NQK_ transposed V^T; NQK_=1920=30*64 -> 64-col tiles split cleanly).
// ---------------------------------------------------------------------------
template <int OUT>
__global__ __launch_bounds__(256) void gemm_bt(
    const short* __restrict__ A, const short* __restrict__ W,
    void* __restrict__ Cv, void* __restrict__ Cv2, int M, int N, int K)
{
    __shared__ short As[2][128 * 64];   // 32 KB
    __shared__ short Bs[2][64 * 64];    // 16 KB

    const int tid  = threadIdx.x;
    const int wv   = tid >> 6;
    const int lane = tid & 63;
    const int wm   = wv >> 1;            // 0..1: 64-row band
    const int wn   = wv & 1;             // 0..1: 32-col band
    const int l16  = lane & 15;
    const int qd   = lane >> 4;

    // bijective chunked XCD swizzle (m204)
    const int nbx = gridDim.x, nby = gridDim.y;
    const int nwg = nbx * nby;
    const int p   = blockIdx.x + blockIdx.y * nbx;    // hw dispatch order
    const int q8  = nwg >> 3, r8 = nwg & 7;
    const int xcd = p & 7, slot = p >> 3;
    const int logical = (xcd < r8) ? xcd * (q8 + 1) + slot
                                   : r8 * (q8 + 1) + (xcd - r8) * q8 + slot;
    const int m0 = (logical / nby) * 128;
    const int n0 = (logical % nby) * 64;

    auto stage = [&](int t, int buf) {
        const int k0 = t * 64;
        // A: 128 rows x 8 granules = 1024, 4 rounds of 256
#pragma unroll
        for (int r = 0; r < 4; ++r) {
            int flat = r * 256 + tid;
            int row = flat >> 3, gd = flat & 7;
            int gs = gd ^ (row & 7);
            glds16(A + (long)(m0 + row) * K + k0 + gs * 8,
                   As[buf] + (r * 256 + wv * 64) * 8);
        }
        // B: 64 rows x 8 granules = 512, 2 rounds
#pragma unroll
        for (int r = 0; r < 2; ++r) {
            int flat = r * 256 + tid;
            int row = flat >> 3, gd = flat & 7;
            int gs = gd ^ (row & 7);
            glds16(W + (long)(n0 + row) * K + k0 + gs * 8,
                   Bs[buf] + (r * 256 + wv * 64) * 8);
        }
    };

    stage(0, 0);
    stage(1, 1);          // 12 glds/thread outstanding

    f32x4 acc[4][2] = {};
    const int NT = K >> 6;

    for (int t = 0; t < NT; ++t) {
        const int buf = t & 1;
        if (t + 1 < NT) asm volatile("s_waitcnt vmcnt(6)" ::: "memory");
        else            asm volatile("s_waitcnt vmcnt(0)" ::: "memory");
        __builtin_amdgcn_s_barrier();
        __builtin_amdgcn_sched_barrier(0);   // no ds_read hoists above barrier

#pragma unroll
        for (int kh = 0; kh < 2; ++kh) {
            bf16x8 af[4], bfr[2];
#pragma unroll
            for (int i = 0; i < 4; ++i) {
                int ar = wm * 64 + i * 16 + l16;
                af[i] = *(const bf16x8*)(As[buf] + ar * 64
                            + (((kh * 4 + qd) ^ (ar & 7)) * 8));
            }
#pragma unroll
            for (int j = 0; j < 2; ++j) {
                int br = wn * 32 + j * 16 + l16;
                bfr[j] = *(const bf16x8*)(Bs[buf] + br * 64
                            + (((kh * 4 + qd) ^ (br & 7)) * 8));
            }
            __builtin_amdgcn_s_setprio(1);
#pragma unroll
            for (int i = 0; i < 4; ++i)
#pragma unroll
                for (int j = 0; j < 2; ++j)
                    acc[i][j] = __builtin_amdgcn_mfma_f32_16x16x32_bf16(
                        af[i], bfr[j], acc[i][j], 0, 0, 0);
            __builtin_amdgcn_s_setprio(0);
        }

        __builtin_amdgcn_sched_barrier(0);
        __builtin_amdgcn_s_barrier();        // all reads of buf done
        if (t + 2 < NT) stage(t + 2, buf);   // refill; stays in flight
    }

    if (OUT == 2) {
        float* C = (float*)Cv;
#pragma unroll
        for (int i = 0; i < 4; ++i) {
            int row0 = m0 + wm * 64 + i * 16 + qd * 4;
#pragma unroll
            for (int j = 0; j < 2; ++j) {
                int col = n0 + wn * 32 + j * 16 + l16;
#pragma unroll
                for (int r = 0; r < 4; ++r)
                    C[(long)(row0 + r) * N + col] = acc[i][j][r];
            }
        }
    } else {  // OUT == 3
        if (n0 < NQK_) {
            short* C = (short*)Cv;
#pragma unroll
            for (int i = 0; i < 4; ++i) {
                int row0 = m0 + wm * 64 + i * 16 + qd * 4;
#pragma unroll
                for (int j = 0; j < 2; ++j) {
                    int col = n0 + wn * 32 + j * 16 + l16;
#pragma unroll
                    for (int r = 0; r < 4; ++r)
                        C[(long)(row0 + r) * NQK_ + col] = f2bf(acc[i][j][r]);
                }
            }
        } else {
            short* C = (short*)Cv2;
#pragma unroll
            for (int i = 0; i < 4; ++i) {
                int row0 = m0 + wm * 64 + i * 16 + qd * 4;
#pragma unroll
                for (int j = 0; j < 2; ++j) {
                    int vcol = n0 - NQK_ + wn * 32 + j * 16 + l16;
                    bf16x4 pk;
                    pk.x = f2bf(acc[i][j][0]); pk.y = f2bf(acc[i][j][1]);
                    pk.z = f2bf(acc[i][j][2]); pk.w = f2bf(acc[i][j][3]);
                    *(bf16x4*)(C + (long)vcol * M_ + row0) = pk;  // V^T
                }
            }
        }
    }
}

// ---------------------------------------------------------------------------
// RMSNorm + RoPE, in place on fused qk buffer (row stride NQK_).
// Q additionally pre-scaled by (1/sqrt(96))*log2(e) -> exp2-domain scores.
// ---------------------------------------------------------------------------
__global__ __launch_bounds__(256) void rms_rope(
    short* __restrict__ qk, const float* __restrict__ qw,
    const float* __restrict__ kw, const int* __restrict__ pos_ids)
{
    int wid  = (int)((blockIdx.x * 256 + threadIdx.x) >> 6);
    int lane = threadIdx.x & 63;

    short* v; const float* w; int row; float qs;
    if (wid < 65536) {                       // q: 4096 rows x 16 heads
        row = wid >> 4;
        v = qk + (long)row * NQK_ + (wid & 15) * 96;
        w = qw;
        qs = 0.14724444f;                    // (1/sqrt(96)) * log2(e)
    } else {                                 // k: 4096 rows x 4 heads
        int t = wid - 65536;
        row = t >> 2;
        v = qk + (long)row * NQK_ + 1536 + (t & 3) * 96;
        w = kw;
        qs = 1.0f;
    }

    float x0 = 0.f, x1 = 0.f;
    if (lane < 48) { x0 = bf2f(v[lane]); x1 = bf2f(v[lane + 48]); }
    float ss = x0 * x0 + x1 * x1;
#pragma unroll
    for (int off = 1; off < 64; off <<= 1) ss += __shfl_xor(ss, off, 64);
    float rr = rsqrtf(ss * (1.0f / 96.0f) + 1e-6f);

    if (lane < 48) {
        int pos = pos_ids[row];
        float y0 = (x0 * rr) * w[lane] * qs;
        float y1 = (x1 * rr) * w[lane + 48] * qs;
        float inv = exp2f(-(float)lane * (13.287712379549449f / 48.0f));
        float fr  = (float)pos * inv;
        float c, s;
        sincosf(fr, &s, &c);
        v[lane]      = f2bf(y0 * c - y1 * s);
        v[lane + 48] = f2bf(y1 * c + y0 * s);
    }
}

// ---------------------------------------------------------------------------
// Flash attention (causal, GQA 4:1). R7 post-mortem: LDS data pipe ~80%
// busy (per wave-unit ~240 cy LDS vs 73 us measured ~= 59 us LDS floor).
// Fix = LDS reads per unit work HALVED: each wave owns 32 q-rows x 32 kv
// (2 wq x 2 we, 256 thr / 4 waves), so every K-frag/V-frag read feeds 2
// MFMAs (16 b128 reads per 28 MFMA vs R7's 15 per 14). R2 proved the shape
// but ran 2 waves/SIMD; here 4 small blocks/CU keep ~16 waves/CU:
// SINGLE-buffered K/V, glds + double-barrier per tile
//   (barrier -> compute(kt) -> barrier -> stage(kt+1)); one block's staging
//   stall hides under the other 3 blocks' compute.
// LDS = 13312 (Ks stride 104, 13-granule pad rows, R7-proven)
//     + 16384 (Vs stride 64, source pre-swizzle g^(row&7), R2-proven)
//     +  8704 (Ps stride 34: 17 coprime 32 -> b128 reads ~2/bank free;
//              b16 writes ~4-way-lite, negligible)
//     = 38400 B -> 4 blocks/CU (153600 < R3's known-bad 159744).
// Grid (32 bh, 32 qi) = 1024 blocks; R6-proven balance map: dispatch quads
// {c, c+256, c+512, c+768} have qt sums == 62 -> equal work per CU.
// Epilogue: we-halves combine through Vs/Ks scratch in 2 g2-phases
// (16 KB each, fits Vs exactly).
// exp2-domain STATIC-MAX softmax: |q|=|k|=sqrt(96), RoPE norm-preserving,
// score*log2e <= 14.14 < 14.5; p = exp2(s - 14.5), no running max.
// qk: fused (M x NQK_)  vt: (KV*VD x M)  out: (B,S,H*128) bf16
// ---------------------------------------------------------------------------
__global__ __launch_bounds__(256) void attn(
    const short* __restrict__ qk, const short* __restrict__ vt,
    short* __restrict__ out)
{
    __shared__ short Ks[64 * 104];       // 13312 B
    __shared__ short Vs[128 * 64];       // 16384 B
    __shared__ short Ps[4][32 * 34];     //  8704 B  -> 38400 B total

    const int tid  = threadIdx.x;
    const int lane = tid & 63;
    const int wv   = tid >> 6;           // 0..3
    const int wq   = wv & 1;             // q sub-tile (32 rows)
    const int we   = wv >> 1;            // kv half (32 cols)
    const int bh   = blockIdx.x;         // 0..31 (fastest dispatch dim)
    const int qi   = blockIdx.y;         // 0..31
    const int b    = bh >> 4, h = bh & 15;
    const int kvh  = h >> 2;
    const int l16  = lane & 15;
    const int qd   = lane >> 4;
    const long bS  = (long)b * S_;

    // balanced qt permutation: qt(qi)+qt(qi+8)+qt(qi+16)+qt(qi+24) == 62
    int qt;
    if      (qi <  8) qt = 31 - 2 * qi;
    else if (qi < 16) qt = 46 - 2 * qi;
    else if (qi < 24) qt = 2 * qi - 32;
    else              qt = 2 * qi - 47;
    const int q0 = qt * 64;

    const short* kbase = qk + bS * NQK_ + 1536 + kvh * 96;
    const short* vbase = vt + (long)kvh * 128 * (B_ * S_) + bS;

    // glds staging (single buffer). K: 64 rows x 13 granules (12 data +
    // 1 pad-from-dummy) = 832 = 3x256 + 64; dest linear (13x16B = row).
    // V: 128 rows x 8 granules = 1024 = 4x256; source granule pre-swizzled
    // g ^ (row&7), dest linear.
    auto stage = [&](int k0) {
#pragma unroll
        for (int r = 0; r < 3; ++r) {
            int flat = r * 256 + tid;
            int row = flat / 13, ch = flat % 13;
            const short* src = (ch < 12)
                ? (kbase + (long)(k0 + row) * NQK_ + ch * 8) : kbase;
            glds16(src, Ks + (r * 256 + wv * 64) * 8);
        }
        if (tid < 64) {      // wv == 0 only; base formula consistent
            int flat = 768 + tid;
            int row = flat / 13, ch = flat % 13;
            const short* src = (ch < 12)
                ? (kbase + (long)(k0 + row) * NQK_ + ch * 8) : kbase;
            glds16(src, Ks + (768 + wv * 64) * 8);
        }
#pragma unroll
        for (int r = 0; r < 4; ++r) {
            int flat = r * 256 + tid;
            int row = flat >> 3;
            int g   = (flat & 7) ^ (row & 7);
            glds16(vbase + (long)row * (B_ * S_) + k0 + g * 8,
                   Vs + (r * 256 + wv * 64) * 8);
        }
    };

    // Q fragments: 2 x 16 rows per wave (32 q-rows total)
    bf16x8 qf[2][3];
#pragma unroll
    for (int g2 = 0; g2 < 2; ++g2) {
        int s = q0 + wq * 32 + g2 * 16 + l16;
        const short* qp = qk + (bS + s) * NQK_ + h * 96 + qd * 8;
        qf[g2][0] = *(const bf16x8*)(qp);
        qf[g2][1] = *(const bf16x8*)(qp + 32);
        qf[g2][2] = *(const bf16x8*)(qp + 64);
    }

    float rs[2][4] = {};          // partial l (this kv half)
    f32x4 o[2][8] = {};           // partial O (this kv half)

    stage(0);   // prologue

    for (int kt = 0; kt <= qt; ++kt) {
        __syncthreads();   // vmcnt(0) per wave: glds(kt) landed everywhere

        // S = Q K^T on this wave's kv half; both q-halves share each kf
        f32x4 sa[2][2] = {};
#pragma unroll
        for (int j = 0; j < 2; ++j)
#pragma unroll
            for (int f = 0; f < 3; ++f) {
                bf16x8 kf = *(const bf16x8*)(Ks
                    + (we * 32 + j * 16 + l16) * 104 + f * 32 + qd * 8);
                sa[0][j] = __builtin_amdgcn_mfma_f32_16x16x32_bf16(
                    qf[0][f], kf, sa[0][j], 0, 0, 0);
                sa[1][j] = __builtin_amdgcn_mfma_f32_16x16x32_bf16(
                    qf[1][f], kf, sa[1][j], 0, 0, 0);
            }

        if (kt == qt) {   // causal mask, diagonal tile only
#pragma unroll
            for (int g2 = 0; g2 < 2; ++g2) {
                int qloc = wq * 32 + g2 * 16 + qd * 4;
#pragma unroll
                for (int j = 0; j < 2; ++j) {
                    int kloc = we * 32 + j * 16 + l16;
#pragma unroll
                    for (int r = 0; r < 4; ++r)
                        if (kloc > qloc + r) sa[g2][j][r] = -30000.0f;
                }
            }
        }

        // static-max softmax: p = exp2(s - M)
#pragma unroll
        for (int g2 = 0; g2 < 2; ++g2)
#pragma unroll
            for (int j = 0; j < 2; ++j)
#pragma unroll
                for (int r = 0; r < 4; ++r) {
                    float p = exp2f(sa[g2][j][r] - 14.5f);
                    rs[g2][r] += p;
                    Ps[wv][(g2 * 16 + qd * 4 + r) * 34 + j * 16 + l16] = f2bf(p);
                }

        // PV: each V-frag read feeds both q-halves
        bf16x8 pf[2];
#pragma unroll
        for (int g2 = 0; g2 < 2; ++g2)
            pf[g2] = *(const bf16x8*)(&Ps[wv][(g2 * 16 + l16) * 34 + qd * 8]);
#pragma unroll
        for (int t = 0; t < 8; ++t) {
            bf16x8 vf = *(const bf16x8*)(Vs + (t * 16 + l16) * 64
                        + (((we * 4 + qd) ^ (l16 & 7)) * 8));
            o[0][t] = __builtin_amdgcn_mfma_f32_16x16x32_bf16(
                pf[0], vf, o[0][t], 0, 0, 0);
            o[1][t] = __builtin_amdgcn_mfma_f32_16x16x32_bf16(
                pf[1], vf, o[1][t], 0, 0, 0);
        }

        if (kt < qt) {
            __syncthreads();          // all waves done reading Ks/Vs
            stage((kt + 1) * 64);     // refill single buffer
        }
    }

    // ---- epilogue: combine kv halves through Vs/Ks scratch, 2 phases ----
    f32x4* ov = (f32x4*)&Vs[0];       // 1024 f32x4 = 16 KB per phase
    f32x4* rv = (f32x4*)&Ks[0];       //  128 f32x4 = 2 KB per phase
#pragma unroll 1
    for (int g2 = 0; g2 < 2; ++g2) {
        __syncthreads();              // reads of Ks/Vs (or prior phase) done
        if (we == 1) {
#pragma unroll
            for (int t = 0; t < 8; ++t)
                ov[(wq * 64 + lane) * 8 + t] = o[g2][t];
            f32x4 rt = { rs[g2][0], rs[g2][1], rs[g2][2], rs[g2][3] };
            rv[wq * 64 + lane] = rt;
        }
        __syncthreads();
        if (we == 0) {
#pragma unroll
            for (int t = 0; t < 8; ++t) {
                f32x4 t2 = ov[(wq * 64 + lane) * 8 + t];
                o[g2][t][0] += t2[0]; o[g2][t][1] += t2[1];
                o[g2][t][2] += t2[2]; o[g2][t][3] += t2[3];
            }
            f32x4 rt = rv[wq * 64 + lane];
            rs[g2][0] += rt[0]; rs[g2][1] += rt[1];
            rs[g2][2] += rt[2]; rs[g2][3] += rt[3];
        }
    }
    if (we == 0) {
#pragma unroll
        for (int g2 = 0; g2 < 2; ++g2) {
            float inv[4];
#pragma unroll
            for (int r = 0; r < 4; ++r) inv[r] = 1.0f / rsum16(rs[g2][r]);
#pragma unroll
            for (int t = 0; t < 8; ++t)
#pragma unroll
                for (int r = 0; r < 4; ++r) {
                    int s = q0 + wq * 32 + g2 * 16 + qd * 4 + r;
                    out[((bS + s) * H_ + h) * 128 + t * 16 + l16] =
                        f2bf(o[g2][t][r] * inv[r]);
                }
        }
    }
}

// ---------------------------------------------------------------------------
extern "C" void kernel_launch(void* const* d_in, const int* in_sizes, int n_in,
                              void* d_out, int out_size, void* d_ws, size_t ws_size,
                              hipStream_t stream)
{
    const float* hs  = (const float*)d_in[0];
    const int*   pos = (const int*)d_in[1];
    const float* Wq  = (const float*)d_in[2];
    const float* Wk  = (const float*)d_in[3];
    const float* Wv  = (const float*)d_in[4];
    const float* Wo  = (const float*)d_in[5];
    const float* qnw = (const float*)d_in[6];
    const float* knw = (const float*)d_in[7];
    float* out = (float*)d_out;
    short* ws  = (short*)d_ws;

    short* hsb   = ws;                         // 4096 x 2048
    short* Wqkvb = hsb + (long)M_ * D_;        // 2432 x 2048 (Wq|Wk|Wv rows)
    short* Wob   = Wqkvb + (long)2432 * D_;    // 2048 x 2048
    short* qk_ws = Wob + (long)D_ * 2048;      // 4096 x 1920 (q | k fused)
    short* vt_ws = qk_ws + (long)M_ * NQK_;    // 512 x 4096  (V^T)
    short* ao_ws = vt_ws + (long)512 * M_;     // 4096 x 2048

    cvt_all<<<17152, 256, 0, stream>>>(hs, Wq, Wk, Wv, Wo, ws);

    gemm_bt<3><<<dim3(32, 38), 256, 0, stream>>>(
        hsb, Wqkvb, qk_ws, vt_ws, M_, 2432, D_);

    rms_rope<<<(65536 + 16384) / 4, 256, 0, stream>>>(qk_ws, qnw, knw, pos);

    attn<<<dim3(32, 32), 256, 0, stream>>>(qk_ws, vt_ws, ao_ws);

    gemm_bt<2><<<dim3(32, 32), 256, 0, stream>>>(
        ao_ws, Wob, (void*)out, nullptr, M_, D_, H_ * VD_);
}